// Round 9
// baseline (667.815 us; speedup 1.0000x reference)
//
#include <hip/hip_runtime.h>
#include <math.h>

#define N_NODES 20000
#define N_EDGES 160000
#define N_CFG   1000
#define OP_FEAT 140
#define CFG_FEAT 24
#define HID     256
#define EMB     128
#define E_TOT   (N_EDGES + N_NODES)
#define KP320   320          // 268 and 280 padded to multiple of 64
#define MPAD    20096        // 157 * 128
#define NW      512          // fused Wl|Wr output width

typedef __attribute__((ext_vector_type(8))) short short8v;
typedef __attribute__((ext_vector_type(4))) float f32x4;

__device__ __forceinline__ short f2bf(float f) {
  unsigned u = __float_as_uint(f);
  unsigned r = (u + 0x7FFFu + ((u >> 16) & 1u)) >> 16;
  return (short)r;
}
__device__ __forceinline__ float bf2f(short s) {
  return __uint_as_float(((unsigned)(unsigned short)s) << 16);
}
__device__ __forceinline__ float gelu_f(float x) {
  return 0.5f * x * (1.0f + erff(x * 0.70710678118654752f));
}

#define GLOAD_LDS(gptr, lptr) __builtin_amdgcn_global_load_lds( \
    (const __attribute__((address_space(1))) void*)(gptr),      \
    (__attribute__((address_space(3))) void*)(lptr), 16, 0, 0)

// ---------------------------------------------------------------- weight prep (merged)
__global__ void prep_weights(
    const float* __restrict__ eW1, const float* __restrict__ eW2,
    const float* __restrict__ lW1, const float* __restrict__ lW2,
    const float* __restrict__ Wl, const float* __restrict__ Wr,
    const float* __restrict__ bl, const float* __restrict__ br,
    short* __restrict__ W1t, short* __restrict__ W2t,
    short* __restrict__ lW1t, short* __restrict__ lW2t,
    short* __restrict__ Wlrt, float* __restrict__ blr)
{
  int i = blockIdx.x * 256 + threadIdx.x;
  const int s1 = HID * KP320;     // W1t  [256][320]
  const int s2 = HID * HID;       // W2t  [256][256]
  const int s3 = HID * KP320;     // lW1t [256][320]
  const int s4 = 128 * HID;       // lW2t [128][256]
  const int s5 = 4 * NW * HID;    // Wlrt [4][512][256]
  const int s6 = 4 * NW;          // blr
  if (i < s1) { int n = i / KP320, k = i % KP320;
    W1t[i] = (k < EMB + OP_FEAT) ? f2bf(eW1[(size_t)k * HID + n]) : (short)0; return; }
  i -= s1;
  if (i < s2) { int n = i >> 8, k = i & 255;
    W2t[i] = f2bf(eW2[(size_t)k * HID + n]); return; }
  i -= s2;
  if (i < s3) { int n = i / KP320, k = i % KP320;
    lW1t[i] = (k < CFG_FEAT + HID) ? f2bf(lW1[(size_t)k * HID + n]) : (short)0; return; }
  i -= s3;
  if (i < s4) { int n = i >> 8, k = i & 255;
    lW2t[i] = f2bf(lW2[(size_t)k * 128 + n]); return; }
  i -= s4;
  if (i < s5) { int l = i >> 17, rem = i & 131071, n = rem >> 8, k = rem & 255;
    float v = (n < HID) ? Wl[(size_t)l * HID * HID + (size_t)k * HID + n]
                        : Wr[(size_t)l * HID * HID + (size_t)k * HID + (n - HID)];
    Wlrt[i] = f2bf(v); return; }
  i -= s5;
  if (i < s6) { int l = i >> 9, j = i & 511;
    blr[i] = (j < HID) ? bl[l * HID + j] : br[l * HID + j - HID]; }
}

// ---------------------------------------------------------------- prep
__global__ __launch_bounds__(256) void prep_kernel(
    const float* __restrict__ node_feat, const float* __restrict__ nf_mean,
    const float* __restrict__ nf_std, const float* __restrict__ emb_table,
    const int* __restrict__ opcode, short* __restrict__ x268b)
{
  int wave = threadIdx.x >> 6;
  int lane = threadIdx.x & 63;
  int row = blockIdx.x * 4 + wave;
  if (row >= N_NODES) return;
  int op = opcode[row];
  float t0 = emb_table[op * EMB + lane];
  float t1 = emb_table[op * EMB + 64 + lane];
  float ss = t0 * t0 + t1 * t1;
  #pragma unroll
  for (int off = 32; off; off >>= 1) ss += __shfl_xor(ss, off);
  float sc = fminf(1.0f, 1.0f / (sqrtf(ss) + 1e-7f));
  short* dst = x268b + (size_t)row * KP320;
  dst[lane] = f2bf(t0 * sc);
  dst[64 + lane] = f2bf(t1 * sc);
  for (int k = lane; k < OP_FEAT; k += 64)
    dst[EMB + k] = f2bf((node_feat[(size_t)row * OP_FEAT + k] - nf_mean[k]) / (nf_std[k] + 1e-4f));
  if (lane < KP320 - EMB - OP_FEAT) dst[EMB + OP_FEAT + lane] = 0;
}

// ---------------------------------------------------------------- MFMA GEMM (2-phase, BK=64)
template<int BM>
__global__ __launch_bounds__(256) void gemm_mfma(
    const short* __restrict__ A, const short* __restrict__ Wt,
    const float* __restrict__ bias, float* __restrict__ C,
    short* __restrict__ Cb, float* __restrict__ stats,
    int M, int N, int Kpad)
{
  constexpr int MI = (BM == 128) ? 4 : 2;
  __shared__ __align__(16) short As[2][8][BM][8];
  __shared__ __align__(16) short Bs[2][8][128][8];
  int tid = threadIdx.x;
  int wave = tid >> 6, lane = tid & 63;
  int bm = blockIdx.x * BM, bn = blockIdx.y * 128;
  int wr = (BM == 128) ? (wave >> 1) * 64 : (wave & 1) * 32;
  int wc = (BM == 128) ? (wave & 1) * 64 : (wave >> 1) * 64;
  int g = lane >> 4, r16 = lane & 15;
  f32x4 acc[MI][4] = {};
  int nt = Kpad >> 6;

  auto STAGE = [&](int t, int b) {
    int k0 = t * 64;
    if constexpr (BM == 128) {
      // 32 issues: c<16 -> A (kk 0..7 x r0 {0,64}), else B
      #pragma unroll
      for (int s = 0; s < 8; s++) {
        int c = wave * 8 + s;
        int mat = c >> 4, rem = c & 15, kk = rem >> 1, r0 = (rem & 1) * 64;
        if (mat == 0)
          GLOAD_LDS(A  + (size_t)(bm + r0 + lane) * Kpad + k0 + kk * 8, &As[b][kk][r0][0]);
        else
          GLOAD_LDS(Wt + (size_t)(bn + r0 + lane) * Kpad + k0 + kk * 8, &Bs[b][kk][r0][0]);
      }
    } else {
      // 24 issues: c<8 -> A (kk=c), else B (kk x r0)
      #pragma unroll
      for (int s = 0; s < 6; s++) {
        int c = wave * 6 + s;
        if (c < 8)
          GLOAD_LDS(A + (size_t)(bm + lane) * Kpad + k0 + c * 8, &As[b][c][0][0]);
        else {
          int c2 = c - 8, kk = c2 >> 1, r0 = (c2 & 1) * 64;
          GLOAD_LDS(Wt + (size_t)(bn + r0 + lane) * Kpad + k0 + kk * 8, &Bs[b][kk][r0][0]);
        }
      }
    }
  };

  STAGE(0, 0);
  for (int t = 0; t < nt; t++) {
    int b = t & 1;
    __syncthreads();                 // buf b ready (vmcnt drained at barrier)
    if (t + 1 < nt) STAGE(t + 1, b ^ 1);
    #pragma unroll
    for (int h = 0; h < 2; h++) {    // two k=32 halves of the 64-wide tile
      short8v af[MI], bfv[4];
      #pragma unroll
      for (int mi = 0; mi < MI; mi++)
        af[mi] = *(const short8v*)&As[b][h * 4 + g][wr + mi * 16 + r16][0];
      #pragma unroll
      for (int ni = 0; ni < 4; ni++)
        bfv[ni] = *(const short8v*)&Bs[b][h * 4 + g][wc + ni * 16 + r16][0];
      #pragma unroll
      for (int mi = 0; mi < MI; mi++)
        #pragma unroll
        for (int ni = 0; ni < 4; ni++)
          acc[mi][ni] = __builtin_amdgcn_mfma_f32_16x16x32_bf16(af[mi], bfv[ni], acc[mi][ni], 0, 0, 0);
    }
  }

  int rg = lane >> 4;
  #pragma unroll
  for (int ni = 0; ni < 4; ni++) {
    int gc = bn + wc + ni * 16 + r16;
    float bv = bias ? bias[gc] : 0.f;
    float s = 0.f, sq = 0.f;
    #pragma unroll
    for (int mi = 0; mi < MI; mi++) {
      #pragma unroll
      for (int r = 0; r < 4; r++) {
        int gr = bm + wr + mi * 16 + rg * 4 + r;
        if (gr < M) {
          float v = acc[mi][ni][r] + bv;
          if (C)  C[(size_t)gr * N + gc] = v;
          if (Cb) Cb[(size_t)gr * N + gc] = f2bf(v);
          s += v; sq += v * v;
        }
      }
    }
    if (stats) {
      s  += __shfl_xor(s, 16);  sq += __shfl_xor(sq, 16);
      s  += __shfl_xor(s, 32);  sq += __shfl_xor(sq, 32);
      if (rg == 0) { atomicAdd(&stats[gc], s); atomicAdd(&stats[N + gc], sq); }
    }
  }
}

// ---------------------------------------------------------------- column stats
__global__ void colstats(const float* __restrict__ X, int M, int C,
                         float* __restrict__ stats)
{
  int c = threadIdx.x;
  int r0 = blockIdx.x * 64;
  int r1 = min(r0 + 64, M);
  float s = 0.f, sq = 0.f;
  for (int r = r0; r < r1; r++) {
    float v = X[(size_t)r * C + c];
    s += v; sq += v * v;
  }
  atomicAdd(&stats[c], s);
  atomicAdd(&stats[C + c], sq);
}

// ---------------------------------------------------------------- norm + gelu (column-major)
__global__ void norm_gelu_col(const float* __restrict__ X, short* __restrict__ Yb,
                              int M, int C, const float* __restrict__ stats,
                              float* __restrict__ psum, unsigned* __restrict__ pmax)
{
  int c = threadIdx.x;
  int r0 = blockIdx.x * 32, r1 = min(r0 + 32, M);
  float invM = 1.0f / (float)M;
  float mean = stats[c] * invM;
  float var = stats[C + c] * invM - mean * mean;
  float inv = rsqrtf(var + 1e-5f);
  float s = 0.f, mx = -INFINITY;
  for (int r = r0; r < r1; r++) {
    float y = gelu_f((X[(size_t)r * C + c] - mean) * inv);
    Yb[(size_t)r * C + c] = f2bf(y);
    s += y; mx = fmaxf(mx, y);
  }
  if (psum) {
    unsigned b = __float_as_uint(mx);
    unsigned enc = (b & 0x80000000u) ? ~b : (b | 0x80000000u);
    atomicAdd(&psum[c], s);
    atomicMax(&pmax[c], enc);
  }
}

// ---------------------------------------------------------------- CSR build
__global__ void edge_count(const int* __restrict__ ei, int* __restrict__ counts) {
  int e = blockIdx.x * blockDim.x + threadIdx.x;
  if (e >= E_TOT) return;
  int dst = (e < N_EDGES) ? ei[N_EDGES + e] : (e - N_EDGES);
  atomicAdd(&counts[dst], 1);
}

__global__ __launch_bounds__(1024) void scan_kernel(const int* __restrict__ counts,
                                                    int* __restrict__ indptr)
{
  __shared__ int sh[1024];
  int t = threadIdx.x;
  const int chunk = (N_NODES + 1023) / 1024;
  int start = t * chunk, end = min(start + chunk, N_NODES);
  int sum = 0;
  for (int i = start; i < end; i++) sum += counts[i];
  sh[t] = sum;
  __syncthreads();
  for (int off = 1; off < 1024; off <<= 1) {
    int v = (t >= off) ? sh[t - off] : 0;
    __syncthreads();
    sh[t] += v;
    __syncthreads();
  }
  int run = (t > 0) ? sh[t - 1] : 0;
  for (int i = start; i < end; i++) { indptr[i] = run; run += counts[i]; }
  if (t == 1023) indptr[N_NODES] = run;
}

__global__ void edge_fill(const int* __restrict__ ei, const int* __restrict__ indptr,
                          int* __restrict__ cursor, int* __restrict__ col)
{
  int e = blockIdx.x * blockDim.x + threadIdx.x;
  if (e >= E_TOT) return;
  int src, dst;
  if (e < N_EDGES) { src = ei[e]; dst = ei[N_EDGES + e]; }
  else             { src = dst = e - N_EDGES; }
  int pos = indptr[dst] + atomicAdd(&cursor[dst], 1);
  col[pos] = src;
}

// ---------------------------------------------------------------- GAT aggregation
// xlr bf16 [N, 512] = [xl | xr]. Wave per node; 8 edges per online-softmax step.
// All arrays statically indexed (rule #20). The validity test (e+b<e1) is
// WAVE-UNIFORM -> guarding the gather skips the load without divergence.
__global__ __launch_bounds__(256) void gat_agg(
    const short* __restrict__ xlr,
    const int* __restrict__ indptr, const int* __restrict__ col,
    const float* __restrict__ att, const float* __restrict__ bias,
    float* __restrict__ out)
{
  int wave = threadIdx.x >> 6, lane = threadIdx.x & 63;
  int node = blockIdx.x * 4 + wave;
  if (node >= N_NODES) return;
  float attc[4], xri[4], o[4] = {0, 0, 0, 0};
  {
    short4 xr4 = *(const short4*)(xlr + (size_t)node * NW + HID + lane * 4);
    #pragma unroll
    for (int k = 0; k < 4; k++) {
      attc[k] = att[lane * 4 + k];
      xri[k] = bf2f(((short*)&xr4)[k]);
    }
  }
  float m = -INFINITY, s = 0.f;
  int e0 = indptr[node], e1 = indptr[node + 1];
  for (int e = e0; e < e1; e += 8) {
    float p[8];
    float xlj[8][4];
    #pragma unroll
    for (int b = 0; b < 8; b++) {
      if (e + b < e1) {                      // wave-uniform: no divergence
        int j = col[e + b];
        short4 xl4 = *(const short4*)(xlr + (size_t)j * NW + lane * 4);
        float pp = 0.f;
        #pragma unroll
        for (int k = 0; k < 4; k++) {
          xlj[b][k] = bf2f(((short*)&xl4)[k]);
          float h = xlj[b][k] + xri[k];
          float lr = h > 0.f ? h : 0.2f * h;
          pp += lr * attc[k];
        }
        p[b] = pp;
      } else {
        p[b] = -INFINITY;
        #pragma unroll
        for (int k = 0; k < 4; k++) xlj[b][k] = 0.f;
      }
    }
    // 8 interleaved wave reductions (independent, pipelined DS chains)
    #pragma unroll
    for (int off = 32; off; off >>= 1) {
      #pragma unroll
      for (int b = 0; b < 8; b++) p[b] += __shfl_xor(p[b], off);
    }
    float mn = m;
    #pragma unroll
    for (int b = 0; b < 8; b++) mn = fmaxf(mn, p[b]);
    float scale = __expf(m - mn);
    float w[8];
    #pragma unroll
    for (int b = 0; b < 8; b++) w[b] = __expf(p[b] - mn);  // invalid -> 0
    float ws = 0.f;
    #pragma unroll
    for (int b = 0; b < 8; b++) ws += w[b];
    s = s * scale + ws;
    #pragma unroll
    for (int k = 0; k < 4; k++) {
      float ok = o[k] * scale;
      #pragma unroll
      for (int b = 0; b < 8; b++) ok += w[b] * xlj[b][k];
      o[k] = ok;
    }
    m = mn;
  }
  float inv = 1.0f / (s + 1e-16f);
  f32x4 ov;
  #pragma unroll
  for (int k = 0; k < 4; k++) ov[k] = o[k] * inv + bias[lane * 4 + k];
  *(f32x4*)(out + (size_t)node * HID + lane * 4) = ov;
}

// ---------------------------------------------------------------- late stage
__device__ __forceinline__ float fdec(unsigned u) {
  unsigned b = (u & 0x80000000u) ? (u & 0x7FFFFFFFu) : ~u;
  return __uint_as_float(b);
}

__global__ void build_xlate(const float* __restrict__ cfg, const float* __restrict__ cmean,
                            const float* __restrict__ cstd, const float* __restrict__ psum,
                            const unsigned* __restrict__ pmax, short* __restrict__ xlateb)
{
  int i = blockIdx.x * blockDim.x + threadIdx.x;
  if (i >= N_CFG * KP320) return;
  int r = i / KP320, c = i % KP320;
  float v;
  if (c < CFG_FEAT) v = (cfg[r * CFG_FEAT + c] - cmean[c]) / (cstd[c] + 1e-4f);
  else if (c < CFG_FEAT + HID) {
    int p = c - CFG_FEAT;
    v = psum[p] * (1.0f / N_NODES) + fdec(pmax[p]);
  } else v = 0.f;
  xlateb[i] = f2bf(v);
}

// pred with fused final norm+gelu (stats from L2 GEMM epilogue)
__global__ __launch_bounds__(64) void pred_kernel(
    const float* __restrict__ h2, const float* __restrict__ stats,
    const float* __restrict__ W, const float* __restrict__ b,
    float* __restrict__ out)
{
  int r = blockIdx.x, lane = threadIdx.x;
  const float invM = 1.0f / (float)N_CFG;
  float v = 0.f;
  #pragma unroll
  for (int t = 0; t < 2; t++) {
    int c = lane + 64 * t;
    float mean = stats[c] * invM;
    float var = stats[128 + c] * invM - mean * mean;
    float y = gelu_f((h2[(size_t)r * 128 + c] - mean) * rsqrtf(var + 1e-5f));
    v += y * W[c];
  }
  #pragma unroll
  for (int off = 32; off; off >>= 1) v += __shfl_xor(v, off);
  if (lane == 0) out[r] = v + b[0];
}

// ================================================================ launch
extern "C" void kernel_launch(void* const* d_in, const int* in_sizes, int n_in,
                              void* d_out, int out_size, void* d_ws, size_t ws_size,
                              hipStream_t stream)
{
  const float* node_feat   = (const float*)d_in[0];
  const float* config_feat = (const float*)d_in[1];
  const float* nf_mean     = (const float*)d_in[2];
  const float* nf_std      = (const float*)d_in[3];
  const float* cf_mean     = (const float*)d_in[4];
  const float* cf_std      = (const float*)d_in[5];
  const float* emb_table   = (const float*)d_in[6];
  const float* early_W1    = (const float*)d_in[7];
  const float* early_W2    = (const float*)d_in[8];
  const float* gat_Wl      = (const float*)d_in[9];
  const float* gat_bl      = (const float*)d_in[10];
  const float* gat_Wr      = (const float*)d_in[11];
  const float* gat_br      = (const float*)d_in[12];
  const float* gat_att     = (const float*)d_in[13];
  const float* gat_bias    = (const float*)d_in[14];
  const float* late_W1     = (const float*)d_in[15];
  const float* late_W2     = (const float*)d_in[16];
  const float* pred_W      = (const float*)d_in[17];
  const float* pred_b      = (const float*)d_in[18];
  const int*   node_opcode = (const int*)d_in[19];
  const int*   edge_index  = (const int*)d_in[20];
  float* out = (float*)d_out;
  (void)in_sizes; (void)n_in; (void)out_size; (void)ws_size;

  char* ws = (char*)d_ws;
  size_t off = 0;
  auto alloc = [&](size_t bytes) -> void* {
    void* p = ws + off;
    off += (bytes + 255) & ~255ull;
    return p;
  };
  short* x268b = (short*)alloc((size_t)MPAD * KP320 * 2);
  float* bufB  = (float*)alloc((size_t)N_NODES * HID * 4);
  short* bufAb = (short*)alloc((size_t)MPAD * HID * 2);
  short* xlr   = (short*)alloc((size_t)N_NODES * NW * 2);
  int* indptr  = (int*)alloc((N_NODES + 1) * 4);
  int* colidx  = (int*)alloc((size_t)E_TOT * 4);
  short* xlateb = (short*)alloc((size_t)1024 * KP320 * 2);
  float* h1    = (float*)alloc((size_t)N_CFG * HID * 4);
  short* h1b   = (short*)alloc((size_t)1024 * HID * 2);
  float* h2    = (float*)alloc((size_t)N_CFG * 128 * 4);
  short* W1t   = (short*)alloc((size_t)HID * KP320 * 2);
  short* W2t   = (short*)alloc((size_t)HID * HID * 2);
  short* Wlrt  = (short*)alloc((size_t)4 * NW * HID * 2);
  float* blr   = (float*)alloc(4 * NW * 4);
  short* lW1t  = (short*)alloc((size_t)HID * KP320 * 2);
  short* lW2t  = (short*)alloc((size_t)128 * HID * 2);

  // ---- contiguous zero region (single memset per call) ----
  float* zbase = (float*)alloc((8 * 1024 + 512 + 2 * N_NODES) * 4);
  float* stats8 = zbase;
  float* psum   = zbase + 8192;
  unsigned* pmax = (unsigned*)(zbase + 8192 + 256);
  int* counts   = (int*)(zbase + 8192 + 512);
  int* cursor   = counts + N_NODES;
  const size_t zbytes = (8 * 1024 + 512 + 2 * N_NODES) * 4;
  auto slot = [&](int s) { return stats8 + s * 1024; };
  // slots: 0=E1 1=E2 2..5=G0..G3 6=L1 7=L2

  auto run_gemm = [&](int BM, const short* A, const short* Wt, const float* bias, float* C,
                      short* Cb, float* stats, int M, int N, int Kpad) {
    dim3 grid((M + BM - 1) / BM, N / 128);
    if (BM == 128)
      hipLaunchKernelGGL(gemm_mfma<128>, grid, dim3(256), 0, stream, A, Wt, bias, C, Cb, stats, M, N, Kpad);
    else
      hipLaunchKernelGGL(gemm_mfma<64>, grid, dim3(256), 0, stream, A, Wt, bias, C, Cb, stats, M, N, Kpad);
  };
  auto run_norm = [&](const float* X, short* Yb, int M, int C, float* stats,
                      float* ps, unsigned* pm) {
    hipLaunchKernelGGL(norm_gelu_col, dim3((M + 31) / 32), dim3(C), 0, stream,
                       X, Yb, M, C, stats, ps, pm);
  };

  hipMemsetAsync(zbase, 0, zbytes, stream);

  // weight prep (one kernel)
  {
    int total = HID * KP320 + HID * HID + HID * KP320 + 128 * HID + 4 * NW * HID + 4 * NW;
    hipLaunchKernelGGL(prep_weights, dim3((total + 255) / 256), dim3(256), 0, stream,
                       early_W1, early_W2, late_W1, late_W2, gat_Wl, gat_Wr, gat_bl, gat_br,
                       W1t, W2t, lW1t, lW2t, Wlrt, blr);
  }

  // CSR build
  hipLaunchKernelGGL(edge_count, dim3((E_TOT + 255) / 256), dim3(256), 0, stream,
                     edge_index, counts);
  hipLaunchKernelGGL(scan_kernel, dim3(1), dim3(1024), 0, stream, counts, indptr);
  hipLaunchKernelGGL(edge_fill, dim3((E_TOT + 255) / 256), dim3(256), 0, stream,
                     edge_index, indptr, cursor, colidx);

  // prep + early MLP
  hipLaunchKernelGGL(prep_kernel, dim3((N_NODES + 3) / 4), dim3(256), 0, stream,
                     node_feat, nf_mean, nf_std, emb_table, node_opcode, x268b);
  run_gemm(64, x268b, W1t, nullptr, bufB, nullptr, slot(0), N_NODES, HID, KP320);
  run_norm(bufB, bufAb, N_NODES, HID, slot(0), nullptr, nullptr);
  run_gemm(64, bufAb, W2t, nullptr, bufB, nullptr, slot(1), N_NODES, HID, HID);
  run_norm(bufB, bufAb, N_NODES, HID, slot(1), nullptr, nullptr);

  // 4 GAT layers
  for (int l = 0; l < 4; l++) {
    run_gemm(128, bufAb, Wlrt + (size_t)l * NW * HID, blr + l * NW, nullptr, xlr, nullptr,
             N_NODES, NW, HID);
    hipLaunchKernelGGL(gat_agg, dim3((N_NODES + 3) / 4), dim3(256), 0, stream,
                       xlr, indptr, colidx, gat_att + l * HID, gat_bias + l * HID, bufB);
    hipLaunchKernelGGL(colstats, dim3((N_NODES + 63) / 64), dim3(HID), 0, stream,
                       bufB, N_NODES, HID, slot(2 + l));
    run_norm(bufB, bufAb, N_NODES, HID, slot(2 + l),
             (l == 3) ? psum : nullptr, (l == 3) ? pmax : nullptr);
  }

  // late MLP
  hipLaunchKernelGGL(build_xlate, dim3((N_CFG * KP320 + 255) / 256), dim3(256), 0, stream,
                     config_feat, cf_mean, cf_std, psum, pmax, xlateb);
  run_gemm(64, xlateb, lW1t, nullptr, h1, nullptr, slot(6), N_CFG, HID, KP320);
  run_norm(h1, h1b, N_CFG, HID, slot(6), nullptr, nullptr);
  run_gemm(64, h1b, lW2t, nullptr, h2, nullptr, slot(7), N_CFG, 128, HID);
  hipLaunchKernelGGL(pred_kernel, dim3(N_CFG), dim3(64), 0, stream,
                     h2, slot(7), pred_W, pred_b, out);
}

// Round 10
// 601.842 us; speedup vs baseline: 1.1096x; 1.1096x over previous
//
#include <hip/hip_runtime.h>
#include <math.h>

#define N_NODES 20000
#define N_EDGES 160000
#define N_CFG   1000
#define OP_FEAT 140
#define CFG_FEAT 24
#define HID     256
#define EMB     128
#define E_TOT   (N_EDGES + N_NODES)
#define K288    288          // 268 and 280 padded to multiple of 32
#define MPAD    20096        // 157 * 128
#define NW      512          // fused Wl|Wr output width

typedef __attribute__((ext_vector_type(8))) short short8v;
typedef __attribute__((ext_vector_type(4))) float f32x4;

__device__ __forceinline__ short f2bf(float f) {
  unsigned u = __float_as_uint(f);
  unsigned r = (u + 0x7FFFu + ((u >> 16) & 1u)) >> 16;
  return (short)r;
}
__device__ __forceinline__ float bf2f(short s) {
  return __uint_as_float(((unsigned)(unsigned short)s) << 16);
}
__device__ __forceinline__ float gelu_f(float x) {
  return 0.5f * x * (1.0f + erff(x * 0.70710678118654752f));
}

#define GLOAD_LDS(gptr, lptr) __builtin_amdgcn_global_load_lds( \
    (const __attribute__((address_space(1))) void*)(gptr),      \
    (__attribute__((address_space(3))) void*)(lptr), 16, 0, 0)

// ---------------------------------------------------------------- weight prep (merged)
__global__ void prep_weights(
    const float* __restrict__ eW1, const float* __restrict__ eW2,
    const float* __restrict__ lW1, const float* __restrict__ lW2,
    const float* __restrict__ Wl, const float* __restrict__ Wr,
    const float* __restrict__ bl, const float* __restrict__ br,
    short* __restrict__ W1t, short* __restrict__ W2t,
    short* __restrict__ lW1t, short* __restrict__ lW2t,
    short* __restrict__ Wlrt, float* __restrict__ blr)
{
  int i = blockIdx.x * 256 + threadIdx.x;
  const int s1 = HID * K288;      // W1t  [256][288]
  const int s2 = HID * HID;       // W2t  [256][256]
  const int s3 = HID * K288;      // lW1t [256][288]
  const int s4 = 128 * HID;       // lW2t [128][256]
  const int s5 = 4 * NW * HID;    // Wlrt [4][512][256]
  const int s6 = 4 * NW;          // blr
  if (i < s1) { int n = i / K288, k = i % K288;
    W1t[i] = (k < EMB + OP_FEAT) ? f2bf(eW1[(size_t)k * HID + n]) : (short)0; return; }
  i -= s1;
  if (i < s2) { int n = i >> 8, k = i & 255;
    W2t[i] = f2bf(eW2[(size_t)k * HID + n]); return; }
  i -= s2;
  if (i < s3) { int n = i / K288, k = i % K288;
    lW1t[i] = (k < CFG_FEAT + HID) ? f2bf(lW1[(size_t)k * HID + n]) : (short)0; return; }
  i -= s3;
  if (i < s4) { int n = i >> 8, k = i & 255;
    lW2t[i] = f2bf(lW2[(size_t)k * 128 + n]); return; }
  i -= s4;
  if (i < s5) { int l = i >> 17, rem = i & 131071, n = rem >> 8, k = rem & 255;
    float v = (n < HID) ? Wl[(size_t)l * HID * HID + (size_t)k * HID + n]
                        : Wr[(size_t)l * HID * HID + (size_t)k * HID + (n - HID)];
    Wlrt[i] = f2bf(v); return; }
  i -= s5;
  if (i < s6) { int l = i >> 9, j = i & 511;
    blr[i] = (j < HID) ? bl[l * HID + j] : br[l * HID + j - HID]; }
}

// ---------------------------------------------------------------- prep
__global__ __launch_bounds__(256) void prep_kernel(
    const float* __restrict__ node_feat, const float* __restrict__ nf_mean,
    const float* __restrict__ nf_std, const float* __restrict__ emb_table,
    const int* __restrict__ opcode, short* __restrict__ x268b)
{
  int wave = threadIdx.x >> 6;
  int lane = threadIdx.x & 63;
  int row = blockIdx.x * 4 + wave;
  if (row >= N_NODES) return;
  int op = opcode[row];
  float t0 = emb_table[op * EMB + lane];
  float t1 = emb_table[op * EMB + 64 + lane];
  float ss = t0 * t0 + t1 * t1;
  #pragma unroll
  for (int off = 32; off; off >>= 1) ss += __shfl_xor(ss, off);
  float sc = fminf(1.0f, 1.0f / (sqrtf(ss) + 1e-7f));
  short* dst = x268b + (size_t)row * K288;
  dst[lane] = f2bf(t0 * sc);
  dst[64 + lane] = f2bf(t1 * sc);
  for (int k = lane; k < OP_FEAT; k += 64)
    dst[EMB + k] = f2bf((node_feat[(size_t)row * OP_FEAT + k] - nf_mean[k]) / (nf_std[k] + 1e-4f));
  if (lane < K288 - EMB - OP_FEAT) dst[EMB + OP_FEAT + lane] = 0;
}

// ---------------------------------------------------------------- MFMA GEMM (2-phase, BK=32)
template<int BM>
__global__ __launch_bounds__(256) void gemm_mfma(
    const short* __restrict__ A, const short* __restrict__ Wt,
    const float* __restrict__ bias, float* __restrict__ C,
    short* __restrict__ Cb, float* __restrict__ stats,
    int M, int N, int Kpad)
{
  constexpr int MI = (BM == 128) ? 4 : 2;
  __shared__ __align__(16) short As[2][4][BM][8];
  __shared__ __align__(16) short Bs[2][4][128][8];
  int tid = threadIdx.x;
  int wave = tid >> 6, lane = tid & 63;
  int bm = blockIdx.x * BM, bn = blockIdx.y * 128;
  int wr = (BM == 128) ? (wave >> 1) * 64 : (wave & 1) * 32;
  int wc = (BM == 128) ? (wave & 1) * 64 : (wave >> 1) * 64;
  int g = lane >> 4, r16 = lane & 15;
  f32x4 acc[MI][4] = {};
  int nt = Kpad >> 5;

  auto STAGE = [&](int t, int b) {
    int k0 = t * 32;
    if constexpr (BM == 128) {
      #pragma unroll
      for (int s2 = 0; s2 < 2; s2++) {
        int s = wave * 2 + s2;
        int sg = s >> 1, r0 = (s & 1) * 64;
        GLOAD_LDS(A  + (size_t)(bm + r0 + lane) * Kpad + k0 + sg * 8, &As[b][sg][r0][0]);
        GLOAD_LDS(Wt + (size_t)(bn + r0 + lane) * Kpad + k0 + sg * 8, &Bs[b][sg][r0][0]);
      }
    } else {
      GLOAD_LDS(A + (size_t)(bm + lane) * Kpad + k0 + wave * 8, &As[b][wave][0][0]);
      #pragma unroll
      for (int s2 = 0; s2 < 2; s2++) {
        int sg = s2 * 2 + (wave >> 1), r0 = (wave & 1) * 64;
        GLOAD_LDS(Wt + (size_t)(bn + r0 + lane) * Kpad + k0 + sg * 8, &Bs[b][sg][r0][0]);
      }
    }
  };

  STAGE(0, 0);
  for (int t = 0; t < nt; t++) {
    int b = t & 1;
    __syncthreads();
    if (t + 1 < nt) STAGE(t + 1, b ^ 1);
    short8v af[MI], bfv[4];
    #pragma unroll
    for (int mi = 0; mi < MI; mi++)
      af[mi] = *(const short8v*)&As[b][g][wr + mi * 16 + r16][0];
    #pragma unroll
    for (int ni = 0; ni < 4; ni++)
      bfv[ni] = *(const short8v*)&Bs[b][g][wc + ni * 16 + r16][0];
    #pragma unroll
    for (int mi = 0; mi < MI; mi++)
      #pragma unroll
      for (int ni = 0; ni < 4; ni++)
        acc[mi][ni] = __builtin_amdgcn_mfma_f32_16x16x32_bf16(af[mi], bfv[ni], acc[mi][ni], 0, 0, 0);
  }

  int rg = lane >> 4;
  #pragma unroll
  for (int ni = 0; ni < 4; ni++) {
    int gc = bn + wc + ni * 16 + r16;
    float bv = bias ? bias[gc] : 0.f;
    float s = 0.f, sq = 0.f;
    #pragma unroll
    for (int mi = 0; mi < MI; mi++) {
      #pragma unroll
      for (int r = 0; r < 4; r++) {
        int gr = bm + wr + mi * 16 + rg * 4 + r;
        if (gr < M) {
          float v = acc[mi][ni][r] + bv;
          if (C)  C[(size_t)gr * N + gc] = v;
          if (Cb) Cb[(size_t)gr * N + gc] = f2bf(v);
          s += v; sq += v * v;
        }
      }
    }
    if (stats) {
      s  += __shfl_xor(s, 16);  sq += __shfl_xor(sq, 16);
      s  += __shfl_xor(s, 32);  sq += __shfl_xor(sq, 32);
      if (rg == 0) { atomicAdd(&stats[gc], s); atomicAdd(&stats[N + gc], sq); }
    }
  }
}

// ---------------------------------------------------------------- column stats
__global__ void colstats(const float* __restrict__ X, int M, int C,
                         float* __restrict__ stats)
{
  int c = threadIdx.x;
  int r0 = blockIdx.x * 64;
  int r1 = min(r0 + 64, M);
  float s = 0.f, sq = 0.f;
  for (int r = r0; r < r1; r++) {
    float v = X[(size_t)r * C + c];
    s += v; sq += v * v;
  }
  atomicAdd(&stats[c], s);
  atomicAdd(&stats[C + c], sq);
}

// ---------------------------------------------------------------- norm + gelu (column-major)
__global__ void norm_gelu_col(const float* __restrict__ X, short* __restrict__ Yb,
                              int M, int C, const float* __restrict__ stats,
                              float* __restrict__ psum, unsigned* __restrict__ pmax)
{
  int c = threadIdx.x;
  int r0 = blockIdx.x * 32, r1 = min(r0 + 32, M);
  float invM = 1.0f / (float)M;
  float mean = stats[c] * invM;
  float var = stats[C + c] * invM - mean * mean;
  float inv = rsqrtf(var + 1e-5f);
  float s = 0.f, mx = -INFINITY;
  for (int r = r0; r < r1; r++) {
    float y = gelu_f((X[(size_t)r * C + c] - mean) * inv);
    Yb[(size_t)r * C + c] = f2bf(y);
    s += y; mx = fmaxf(mx, y);
  }
  if (psum) {
    unsigned b = __float_as_uint(mx);
    unsigned enc = (b & 0x80000000u) ? ~b : (b | 0x80000000u);
    atomicAdd(&psum[c], s);
    atomicMax(&pmax[c], enc);
  }
}

// ---------------------------------------------------------------- CSR build
__global__ void edge_count(const int* __restrict__ ei, int* __restrict__ counts) {
  int e = blockIdx.x * blockDim.x + threadIdx.x;
  if (e >= E_TOT) return;
  int dst = (e < N_EDGES) ? ei[N_EDGES + e] : (e - N_EDGES);
  atomicAdd(&counts[dst], 1);
}

__global__ __launch_bounds__(1024) void scan_kernel(const int* __restrict__ counts,
                                                    int* __restrict__ indptr)
{
  __shared__ int sh[1024];
  int t = threadIdx.x;
  const int chunk = (N_NODES + 1023) / 1024;
  int start = t * chunk, end = min(start + chunk, N_NODES);
  int sum = 0;
  for (int i = start; i < end; i++) sum += counts[i];
  sh[t] = sum;
  __syncthreads();
  for (int off = 1; off < 1024; off <<= 1) {
    int v = (t >= off) ? sh[t - off] : 0;
    __syncthreads();
    sh[t] += v;
    __syncthreads();
  }
  int run = (t > 0) ? sh[t - 1] : 0;
  for (int i = start; i < end; i++) { indptr[i] = run; run += counts[i]; }
  if (t == 1023) indptr[N_NODES] = run;
}

__global__ void edge_fill(const int* __restrict__ ei, const int* __restrict__ indptr,
                          int* __restrict__ cursor, int* __restrict__ col)
{
  int e = blockIdx.x * blockDim.x + threadIdx.x;
  if (e >= E_TOT) return;
  int src, dst;
  if (e < N_EDGES) { src = ei[e]; dst = ei[N_EDGES + e]; }
  else             { src = dst = e - N_EDGES; }
  int pos = indptr[dst] + atomicAdd(&cursor[dst], 1);
  col[pos] = src;
}

// ---------------------------------------------------------------- GAT aggregation
// xlr bf16 [N, 512] = [xl | xr]. Wave per node. 8 edges per iteration feeding
// TWO independent online-softmax chains (assoc. merge at end) — halves the
// serial chain depth vs one chain. Branch-free pad (col[e0] always valid),
// all arrays statically indexed (rule #20). NaN guards: sc=1 when m==mn
// (covers -INF/-INF empty-chain case); w=0 for pad slots.
__global__ __launch_bounds__(256) void gat_agg(
    const short* __restrict__ xlr,
    const int* __restrict__ indptr, const int* __restrict__ col,
    const float* __restrict__ att, const float* __restrict__ bias,
    float* __restrict__ out)
{
  int wave = threadIdx.x >> 6, lane = threadIdx.x & 63;
  int node = blockIdx.x * 4 + wave;
  if (node >= N_NODES) return;
  float attc[4], xri[4];
  {
    short4 xr4 = *(const short4*)(xlr + (size_t)node * NW + HID + lane * 4);
    #pragma unroll
    for (int k = 0; k < 4; k++) {
      attc[k] = att[lane * 4 + k];
      xri[k] = bf2f(((short*)&xr4)[k]);
    }
  }
  float m0 = -INFINITY, s0 = 0.f, o0[4] = {0, 0, 0, 0};
  float m1 = -INFINITY, s1 = 0.f, o1[4] = {0, 0, 0, 0};
  int e0 = indptr[node], e1 = indptr[node + 1];
  for (int e = e0; e < e1; e += 8) {
    float p[8];
    float xlj[8][4];
    #pragma unroll
    for (int b = 0; b < 8; b++) {
      bool valid = (e + b) < e1;
      int j = col[valid ? e + b : e0];        // e0 always valid (self-loop)
      short4 xl4 = *(const short4*)(xlr + (size_t)j * NW + lane * 4);
      float pp = 0.f;
      #pragma unroll
      for (int k = 0; k < 4; k++) {
        xlj[b][k] = bf2f(((short*)&xl4)[k]);
        float h = xlj[b][k] + xri[k];
        float lr = h > 0.f ? h : 0.2f * h;
        pp += lr * attc[k];
      }
      p[b] = valid ? pp : -INFINITY;
    }
    // 8 interleaved wave reductions (independent, pipelined)
    #pragma unroll
    for (int off = 32; off; off >>= 1) {
      #pragma unroll
      for (int b = 0; b < 8; b++) p[b] += __shfl_xor(p[b], off);
    }
    // chain 0 <- slots 0..3
    {
      float mn = fmaxf(m0, fmaxf(fmaxf(p[0], p[1]), fmaxf(p[2], p[3])));
      float sc = (m0 == mn) ? 1.0f : __expf(m0 - mn);
      float w[4];
      #pragma unroll
      for (int b = 0; b < 4; b++)
        w[b] = (p[b] > -1e37f) ? __expf(p[b] - mn) : 0.f;
      s0 = s0 * sc + w[0] + w[1] + w[2] + w[3];
      #pragma unroll
      for (int k = 0; k < 4; k++)
        o0[k] = o0[k] * sc + w[0] * xlj[0][k] + w[1] * xlj[1][k]
                           + w[2] * xlj[2][k] + w[3] * xlj[3][k];
      m0 = mn;
    }
    // chain 1 <- slots 4..7 (independent of chain 0)
    {
      float mn = fmaxf(m1, fmaxf(fmaxf(p[4], p[5]), fmaxf(p[6], p[7])));
      float sc = (m1 == mn) ? 1.0f : __expf(m1 - mn);
      float w[4];
      #pragma unroll
      for (int b = 0; b < 4; b++)
        w[b] = (p[4 + b] > -1e37f) ? __expf(p[4 + b] - mn) : 0.f;
      s1 = s1 * sc + w[0] + w[1] + w[2] + w[3];
      #pragma unroll
      for (int k = 0; k < 4; k++)
        o1[k] = o1[k] * sc + w[0] * xlj[4][k] + w[1] * xlj[5][k]
                           + w[2] * xlj[6][k] + w[3] * xlj[7][k];
      m1 = mn;
    }
  }
  // merge chains (associative online-softmax combine; empty chain1 -> a1=0)
  float mm = fmaxf(m0, m1);
  float a0 = (m0 == mm) ? 1.0f : __expf(m0 - mm);
  float a1 = (m1 > -1e37f) ? ((m1 == mm) ? 1.0f : __expf(m1 - mm)) : 0.f;
  float s = s0 * a0 + s1 * a1;
  float inv = 1.0f / (s + 1e-16f);
  f32x4 ov;
  #pragma unroll
  for (int k = 0; k < 4; k++)
    ov[k] = (o0[k] * a0 + o1[k] * a1) * inv + bias[lane * 4 + k];
  *(f32x4*)(out + (size_t)node * HID + lane * 4) = ov;
}

// ---------------------------------------------------------------- late stage
__device__ __forceinline__ float fdec(unsigned u) {
  unsigned b = (u & 0x80000000u) ? (u & 0x7FFFFFFFu) : ~u;
  return __uint_as_float(b);
}

__global__ void build_xlate(const float* __restrict__ cfg, const float* __restrict__ cmean,
                            const float* __restrict__ cstd, const float* __restrict__ psum,
                            const unsigned* __restrict__ pmax, short* __restrict__ xlateb)
{
  int i = blockIdx.x * blockDim.x + threadIdx.x;
  if (i >= N_CFG * K288) return;
  int r = i / K288, c = i % K288;
  float v;
  if (c < CFG_FEAT) v = (cfg[r * CFG_FEAT + c] - cmean[c]) / (cstd[c] + 1e-4f);
  else if (c < CFG_FEAT + HID) {
    int p = c - CFG_FEAT;
    v = psum[p] * (1.0f / N_NODES) + fdec(pmax[p]);
  } else v = 0.f;
  xlateb[i] = f2bf(v);
}

// pred with fused final norm+gelu (stats from L2 GEMM epilogue)
__global__ __launch_bounds__(64) void pred_kernel(
    const float* __restrict__ h2, const float* __restrict__ stats,
    const float* __restrict__ W, const float* __restrict__ b,
    float* __restrict__ out)
{
  int r = blockIdx.x, lane = threadIdx.x;
  const float invM = 1.0f / (float)N_CFG;
  float v = 0.f;
  #pragma unroll
  for (int t = 0; t < 2; t++) {
    int c = lane + 64 * t;
    float mean = stats[c] * invM;
    float var = stats[128 + c] * invM - mean * mean;
    float y = gelu_f((h2[(size_t)r * 128 + c] - mean) * rsqrtf(var + 1e-5f));
    v += y * W[c];
  }
  #pragma unroll
  for (int off = 32; off; off >>= 1) v += __shfl_xor(v, off);
  if (lane == 0) out[r] = v + b[0];
}

// ================================================================ launch
extern "C" void kernel_launch(void* const* d_in, const int* in_sizes, int n_in,
                              void* d_out, int out_size, void* d_ws, size_t ws_size,
                              hipStream_t stream)
{
  const float* node_feat   = (const float*)d_in[0];
  const float* config_feat = (const float*)d_in[1];
  const float* nf_mean     = (const float*)d_in[2];
  const float* nf_std      = (const float*)d_in[3];
  const float* cf_mean     = (const float*)d_in[4];
  const float* cf_std      = (const float*)d_in[5];
  const float* emb_table   = (const float*)d_in[6];
  const float* early_W1    = (const float*)d_in[7];
  const float* early_W2    = (const float*)d_in[8];
  const float* gat_Wl      = (const float*)d_in[9];
  const float* gat_bl      = (const float*)d_in[10];
  const float* gat_Wr      = (const float*)d_in[11];
  const float* gat_br      = (const float*)d_in[12];
  const float* gat_att     = (const float*)d_in[13];
  const float* gat_bias    = (const float*)d_in[14];
  const float* late_W1     = (const float*)d_in[15];
  const float* late_W2     = (const float*)d_in[16];
  const float* pred_W      = (const float*)d_in[17];
  const float* pred_b      = (const float*)d_in[18];
  const int*   node_opcode = (const int*)d_in[19];
  const int*   edge_index  = (const int*)d_in[20];
  float* out = (float*)d_out;
  (void)in_sizes; (void)n_in; (void)out_size; (void)ws_size;

  char* ws = (char*)d_ws;
  size_t off = 0;
  auto alloc = [&](size_t bytes) -> void* {
    void* p = ws + off;
    off += (bytes + 255) & ~255ull;
    return p;
  };
  short* x268b = (short*)alloc((size_t)MPAD * K288 * 2);
  float* bufB  = (float*)alloc((size_t)N_NODES * HID * 4);
  short* bufAb = (short*)alloc((size_t)MPAD * HID * 2);
  short* xlr   = (short*)alloc((size_t)N_NODES * NW * 2);
  int* indptr  = (int*)alloc((N_NODES + 1) * 4);
  int* colidx  = (int*)alloc((size_t)E_TOT * 4);
  short* xlateb = (short*)alloc((size_t)1024 * K288 * 2);
  float* h1    = (float*)alloc((size_t)N_CFG * HID * 4);
  short* h1b   = (short*)alloc((size_t)1024 * HID * 2);
  float* h2    = (float*)alloc((size_t)N_CFG * 128 * 4);
  short* W1t   = (short*)alloc((size_t)HID * K288 * 2);
  short* W2t   = (short*)alloc((size_t)HID * HID * 2);
  short* Wlrt  = (short*)alloc((size_t)4 * NW * HID * 2);
  float* blr   = (float*)alloc(4 * NW * 4);
  short* lW1t  = (short*)alloc((size_t)HID * K288 * 2);
  short* lW2t  = (short*)alloc((size_t)128 * HID * 2);

  // ---- contiguous zero region (single memset per call) ----
  float* zbase = (float*)alloc((8 * 1024 + 512 + 2 * N_NODES) * 4);
  float* stats8 = zbase;
  float* psum   = zbase + 8192;
  unsigned* pmax = (unsigned*)(zbase + 8192 + 256);
  int* counts   = (int*)(zbase + 8192 + 512);
  int* cursor   = counts + N_NODES;
  const size_t zbytes = (8 * 1024 + 512 + 2 * N_NODES) * 4;
  auto slot = [&](int s) { return stats8 + s * 1024; };
  // slots: 0=E1 1=E2 2..5=G0..G3 6=L1 7=L2

  auto run_gemm = [&](int BM, const short* A, const short* Wt, const float* bias, float* C,
                      short* Cb, float* stats, int M, int N, int Kpad) {
    dim3 grid((M + BM - 1) / BM, N / 128);
    if (BM == 128)
      hipLaunchKernelGGL(gemm_mfma<128>, grid, dim3(256), 0, stream, A, Wt, bias, C, Cb, stats, M, N, Kpad);
    else
      hipLaunchKernelGGL(gemm_mfma<64>, grid, dim3(256), 0, stream, A, Wt, bias, C, Cb, stats, M, N, Kpad);
  };
  auto run_norm = [&](const float* X, short* Yb, int M, int C, float* stats,
                      float* ps, unsigned* pm) {
    hipLaunchKernelGGL(norm_gelu_col, dim3((M + 31) / 32), dim3(C), 0, stream,
                       X, Yb, M, C, stats, ps, pm);
  };

  hipMemsetAsync(zbase, 0, zbytes, stream);

  // weight prep (one kernel)
  {
    int total = HID * K288 + HID * HID + HID * K288 + 128 * HID + 4 * NW * HID + 4 * NW;
    hipLaunchKernelGGL(prep_weights, dim3((total + 255) / 256), dim3(256), 0, stream,
                       early_W1, early_W2, late_W1, late_W2, gat_Wl, gat_Wr, gat_bl, gat_br,
                       W1t, W2t, lW1t, lW2t, Wlrt, blr);
  }

  // CSR build
  hipLaunchKernelGGL(edge_count, dim3((E_TOT + 255) / 256), dim3(256), 0, stream,
                     edge_index, counts);
  hipLaunchKernelGGL(scan_kernel, dim3(1), dim3(1024), 0, stream, counts, indptr);
  hipLaunchKernelGGL(edge_fill, dim3((E_TOT + 255) / 256), dim3(256), 0, stream,
                     edge_index, indptr, cursor, colidx);

  // prep + early MLP
  hipLaunchKernelGGL(prep_kernel, dim3((N_NODES + 3) / 4), dim3(256), 0, stream,
                     node_feat, nf_mean, nf_std, emb_table, node_opcode, x268b);
  run_gemm(64, x268b, W1t, nullptr, bufB, nullptr, slot(0), N_NODES, HID, K288);
  run_norm(bufB, bufAb, N_NODES, HID, slot(0), nullptr, nullptr);
  run_gemm(64, bufAb, W2t, nullptr, bufB, nullptr, slot(1), N_NODES, HID, HID);
  run_norm(bufB, bufAb, N_NODES, HID, slot(1), nullptr, nullptr);

  // 4 GAT layers
  for (int l = 0; l < 4; l++) {
    run_gemm(128, bufAb, Wlrt + (size_t)l * NW * HID, blr + l * NW, nullptr, xlr, nullptr,
             N_NODES, NW, HID);
    hipLaunchKernelGGL(gat_agg, dim3((N_NODES + 3) / 4), dim3(256), 0, stream,
                       xlr, indptr, colidx, gat_att + l * HID, gat_bias + l * HID, bufB);
    hipLaunchKernelGGL(colstats, dim3((N_NODES + 63) / 64), dim3(HID), 0, stream,
                       bufB, N_NODES, HID, slot(2 + l));
    run_norm(bufB, bufAb, N_NODES, HID, slot(2 + l),
             (l == 3) ? psum : nullptr, (l == 3) ? pmax : nullptr);
  }

  // late MLP
  hipLaunchKernelGGL(build_xlate, dim3((N_CFG * K288 + 255) / 256), dim3(256), 0, stream,
                     config_feat, cf_mean, cf_std, psum, pmax, xlateb);
  run_gemm(64, xlateb, lW1t, nullptr, h1, nullptr, slot(6), N_CFG, HID, K288);
  run_norm(h1, h1b, N_CFG, HID, slot(6), nullptr, nullptr);
  run_gemm(64, h1b, lW2t, nullptr, h2, nullptr, slot(7), N_CFG, 128, HID);
  hipLaunchKernelGGL(pred_kernel, dim3(N_CFG), dim3(64), 0, stream,
                     h2, slot(7), pred_W, pred_b, out);
}

// Round 11
// 560.776 us; speedup vs baseline: 1.1909x; 1.0732x over previous
//
#include <hip/hip_runtime.h>
#include <math.h>

#define N_NODES 20000
#define N_EDGES 160000
#define N_CFG   1000
#define OP_FEAT 140
#define CFG_FEAT 24
#define HID     256
#define EMB     128
#define E_TOT   (N_EDGES + N_NODES)
#define K288    288          // 268 and 280 padded to multiple of 32
#define MPAD    20096        // 157 * 128
#define NW      512          // fused Wl|Wr output width

typedef __attribute__((ext_vector_type(8))) short short8v;
typedef __attribute__((ext_vector_type(4))) float f32x4;

__device__ __forceinline__ short f2bf(float f) {
  unsigned u = __float_as_uint(f);
  unsigned r = (u + 0x7FFFu + ((u >> 16) & 1u)) >> 16;
  return (short)r;
}
__device__ __forceinline__ float bf2f(short s) {
  return __uint_as_float(((unsigned)(unsigned short)s) << 16);
}
__device__ __forceinline__ float gelu_f(float x) {
  return 0.5f * x * (1.0f + erff(x * 0.70710678118654752f));
}

#define GLOAD_LDS(gptr, lptr) __builtin_amdgcn_global_load_lds( \
    (const __attribute__((address_space(1))) void*)(gptr),      \
    (__attribute__((address_space(3))) void*)(lptr), 16, 0, 0)

// ---------------------------------------------------------------- weight prep (merged)
__global__ void prep_weights(
    const float* __restrict__ eW1, const float* __restrict__ eW2,
    const float* __restrict__ lW1, const float* __restrict__ lW2,
    const float* __restrict__ Wl, const float* __restrict__ Wr,
    const float* __restrict__ bl, const float* __restrict__ br,
    short* __restrict__ W1t, short* __restrict__ W2t,
    short* __restrict__ lW1t, short* __restrict__ lW2t,
    short* __restrict__ Wlrt, float* __restrict__ blr)
{
  int i = blockIdx.x * 256 + threadIdx.x;
  const int s1 = HID * K288;      // W1t  [256][288]
  const int s2 = HID * HID;       // W2t  [256][256]
  const int s3 = HID * K288;      // lW1t [256][288]
  const int s4 = 128 * HID;       // lW2t [128][256]
  const int s5 = 4 * NW * HID;    // Wlrt [4][512][256]
  const int s6 = 4 * NW;          // blr
  if (i < s1) { int n = i / K288, k = i % K288;
    W1t[i] = (k < EMB + OP_FEAT) ? f2bf(eW1[(size_t)k * HID + n]) : (short)0; return; }
  i -= s1;
  if (i < s2) { int n = i >> 8, k = i & 255;
    W2t[i] = f2bf(eW2[(size_t)k * HID + n]); return; }
  i -= s2;
  if (i < s3) { int n = i / K288, k = i % K288;
    lW1t[i] = (k < CFG_FEAT + HID) ? f2bf(lW1[(size_t)k * HID + n]) : (short)0; return; }
  i -= s3;
  if (i < s4) { int n = i >> 8, k = i & 255;
    lW2t[i] = f2bf(lW2[(size_t)k * 128 + n]); return; }
  i -= s4;
  if (i < s5) { int l = i >> 17, rem = i & 131071, n = rem >> 8, k = rem & 255;
    float v = (n < HID) ? Wl[(size_t)l * HID * HID + (size_t)k * HID + n]
                        : Wr[(size_t)l * HID * HID + (size_t)k * HID + (n - HID)];
    Wlrt[i] = f2bf(v); return; }
  i -= s5;
  if (i < s6) { int l = i >> 9, j = i & 511;
    blr[i] = (j < HID) ? bl[l * HID + j] : br[l * HID + j - HID]; }
}

// ---------------------------------------------------------------- prep
__global__ __launch_bounds__(256) void prep_kernel(
    const float* __restrict__ node_feat, const float* __restrict__ nf_mean,
    const float* __restrict__ nf_std, const float* __restrict__ emb_table,
    const int* __restrict__ opcode, short* __restrict__ x268b)
{
  int wave = threadIdx.x >> 6;
  int lane = threadIdx.x & 63;
  int row = blockIdx.x * 4 + wave;
  if (row >= N_NODES) return;
  int op = opcode[row];
  float t0 = emb_table[op * EMB + lane];
  float t1 = emb_table[op * EMB + 64 + lane];
  float ss = t0 * t0 + t1 * t1;
  #pragma unroll
  for (int off = 32; off; off >>= 1) ss += __shfl_xor(ss, off);
  float sc = fminf(1.0f, 1.0f / (sqrtf(ss) + 1e-7f));
  short* dst = x268b + (size_t)row * K288;
  dst[lane] = f2bf(t0 * sc);
  dst[64 + lane] = f2bf(t1 * sc);
  for (int k = lane; k < OP_FEAT; k += 64)
    dst[EMB + k] = f2bf((node_feat[(size_t)row * OP_FEAT + k] - nf_mean[k]) / (nf_std[k] + 1e-4f));
  if (lane < K288 - EMB - OP_FEAT) dst[EMB + OP_FEAT + lane] = 0;
}

// ---------------------------------------------------------------- MFMA GEMM (2-phase, BK=32)
// 128x128 (4 waves 2x2 of 64x64) or 64x64 (4 waves 2x2 of 32x32).
template<int BM, int BN>
__global__ __launch_bounds__(256) void gemm_mfma(
    const short* __restrict__ A, const short* __restrict__ Wt,
    const float* __restrict__ bias, float* __restrict__ C,
    short* __restrict__ Cb, float* __restrict__ stats,
    int M, int N, int Kpad)
{
  constexpr int MI = (BM == 128) ? 4 : 2;
  constexpr int NI = (BN == 128) ? 4 : 2;
  __shared__ __align__(16) short As[2][4][BM][8];
  __shared__ __align__(16) short Bs[2][4][BN][8];
  int tid = threadIdx.x;
  int wave = tid >> 6, lane = tid & 63;
  int bm = blockIdx.x * BM, bn = blockIdx.y * BN;
  int wr = (BM == 128) ? (wave >> 1) * 64 : (wave >> 1) * 32;
  int wc = (BM == 128) ? (wave & 1) * 64 : (wave & 1) * 32;
  int g = lane >> 4, r16 = lane & 15;
  f32x4 acc[MI][NI] = {};
  int nt = Kpad >> 5;

  auto STAGE = [&](int t, int b) {
    int k0 = t * 32;
    if constexpr (BM == 128) {
      #pragma unroll
      for (int s2 = 0; s2 < 2; s2++) {
        int s = wave * 2 + s2;
        int sg = s >> 1, r0 = (s & 1) * 64;
        GLOAD_LDS(A  + (size_t)(bm + r0 + lane) * Kpad + k0 + sg * 8, &As[b][sg][r0][0]);
        GLOAD_LDS(Wt + (size_t)(bn + r0 + lane) * Kpad + k0 + sg * 8, &Bs[b][sg][r0][0]);
      }
    } else {
      // 64x64: one A-load + one B-load per thread stages the full tile
      GLOAD_LDS(A  + (size_t)(bm + lane) * Kpad + k0 + wave * 8, &As[b][wave][0][0]);
      GLOAD_LDS(Wt + (size_t)(bn + lane) * Kpad + k0 + wave * 8, &Bs[b][wave][0][0]);
    }
  };

  STAGE(0, 0);
  for (int t = 0; t < nt; t++) {
    int b = t & 1;
    __syncthreads();                 // buf b ready (vmcnt drained at barrier)
    if (t + 1 < nt) STAGE(t + 1, b ^ 1);
    short8v af[MI], bfv[NI];
    #pragma unroll
    for (int mi = 0; mi < MI; mi++)
      af[mi] = *(const short8v*)&As[b][g][wr + mi * 16 + r16][0];
    #pragma unroll
    for (int ni = 0; ni < NI; ni++)
      bfv[ni] = *(const short8v*)&Bs[b][g][wc + ni * 16 + r16][0];
    #pragma unroll
    for (int mi = 0; mi < MI; mi++)
      #pragma unroll
      for (int ni = 0; ni < NI; ni++)
        acc[mi][ni] = __builtin_amdgcn_mfma_f32_16x16x32_bf16(af[mi], bfv[ni], acc[mi][ni], 0, 0, 0);
  }

  int rg = lane >> 4;
  #pragma unroll
  for (int ni = 0; ni < NI; ni++) {
    int gc = bn + wc + ni * 16 + r16;
    float bv = bias ? bias[gc] : 0.f;
    float s = 0.f, sq = 0.f;
    #pragma unroll
    for (int mi = 0; mi < MI; mi++) {
      #pragma unroll
      for (int r = 0; r < 4; r++) {
        int gr = bm + wr + mi * 16 + rg * 4 + r;
        if (gr < M) {
          float v = acc[mi][ni][r] + bv;
          if (C)  C[(size_t)gr * N + gc] = v;
          if (Cb) Cb[(size_t)gr * N + gc] = f2bf(v);
          s += v; sq += v * v;
        }
      }
    }
    if (stats) {
      s  += __shfl_xor(s, 16);  sq += __shfl_xor(sq, 16);
      s  += __shfl_xor(s, 32);  sq += __shfl_xor(sq, 32);
      if (rg == 0) { atomicAdd(&stats[gc], s); atomicAdd(&stats[N + gc], sq); }
    }
  }
}

// ---------------------------------------------------------------- column stats
__global__ void colstats(const float* __restrict__ X, int M, int C,
                         float* __restrict__ stats)
{
  int c = threadIdx.x;
  int r0 = blockIdx.x * 64;
  int r1 = min(r0 + 64, M);
  float s = 0.f, sq = 0.f;
  for (int r = r0; r < r1; r++) {
    float v = X[(size_t)r * C + c];
    s += v; sq += v * v;
  }
  atomicAdd(&stats[c], s);
  atomicAdd(&stats[C + c], sq);
}

// ---------------------------------------------------------------- norm + gelu (column-major)
__global__ void norm_gelu_col(const float* __restrict__ X, short* __restrict__ Yb,
                              int M, int C, const float* __restrict__ stats,
                              float* __restrict__ psum, unsigned* __restrict__ pmax)
{
  int c = threadIdx.x;
  int r0 = blockIdx.x * 32, r1 = min(r0 + 32, M);
  float invM = 1.0f / (float)M;
  float mean = stats[c] * invM;
  float var = stats[C + c] * invM - mean * mean;
  float inv = rsqrtf(var + 1e-5f);
  float s = 0.f, mx = -INFINITY;
  for (int r = r0; r < r1; r++) {
    float y = gelu_f((X[(size_t)r * C + c] - mean) * inv);
    Yb[(size_t)r * C + c] = f2bf(y);
    s += y; mx = fmaxf(mx, y);
  }
  if (psum) {
    unsigned b = __float_as_uint(mx);
    unsigned enc = (b & 0x80000000u) ? ~b : (b | 0x80000000u);
    atomicAdd(&psum[c], s);
    atomicMax(&pmax[c], enc);
  }
}

// ---------------------------------------------------------------- CSR build
__global__ void edge_count(const int* __restrict__ ei, int* __restrict__ counts) {
  int e = blockIdx.x * blockDim.x + threadIdx.x;
  if (e >= E_TOT) return;
  int dst = (e < N_EDGES) ? ei[N_EDGES + e] : (e - N_EDGES);
  atomicAdd(&counts[dst], 1);
}

__global__ __launch_bounds__(1024) void scan_kernel(const int* __restrict__ counts,
                                                    int* __restrict__ indptr)
{
  __shared__ int sh[1024];
  int t = threadIdx.x;
  const int chunk = (N_NODES + 1023) / 1024;
  int start = t * chunk, end = min(start + chunk, N_NODES);
  int sum = 0;
  for (int i = start; i < end; i++) sum += counts[i];
  sh[t] = sum;
  __syncthreads();
  for (int off = 1; off < 1024; off <<= 1) {
    int v = (t >= off) ? sh[t - off] : 0;
    __syncthreads();
    sh[t] += v;
    __syncthreads();
  }
  int run = (t > 0) ? sh[t - 1] : 0;
  for (int i = start; i < end; i++) { indptr[i] = run; run += counts[i]; }
  if (t == 1023) indptr[N_NODES] = run;
}

__global__ void edge_fill(const int* __restrict__ ei, const int* __restrict__ indptr,
                          int* __restrict__ cursor, int* __restrict__ col)
{
  int e = blockIdx.x * blockDim.x + threadIdx.x;
  if (e >= E_TOT) return;
  int src, dst;
  if (e < N_EDGES) { src = ei[e]; dst = ei[N_EDGES + e]; }
  else             { src = dst = e - N_EDGES; }
  int pos = indptr[dst] + atomicAdd(&cursor[dst], 1);
  col[pos] = src;
}

// ---------------------------------------------------------------- GAT aggregation
// (the 564-us round-7 version) xlr bf16 [N,512]=[xl|xr]. Wave per node; 4 edges
// per online-softmax step, branch-free pad via col[e0], all static indices.
__global__ __launch_bounds__(256) void gat_agg(
    const short* __restrict__ xlr,
    const int* __restrict__ indptr, const int* __restrict__ col,
    const float* __restrict__ att, const float* __restrict__ bias,
    float* __restrict__ out)
{
  int wave = threadIdx.x >> 6, lane = threadIdx.x & 63;
  int node = blockIdx.x * 4 + wave;
  if (node >= N_NODES) return;
  float attc[4], xri[4], o[4] = {0, 0, 0, 0};
  {
    short4 xr4 = *(const short4*)(xlr + (size_t)node * NW + HID + lane * 4);
    #pragma unroll
    for (int k = 0; k < 4; k++) {
      attc[k] = att[lane * 4 + k];
      xri[k] = bf2f(((short*)&xr4)[k]);
    }
  }
  float m = -INFINITY, s = 0.f;
  int e0 = indptr[node], e1 = indptr[node + 1];
  for (int e = e0; e < e1; e += 4) {
    float p[4];
    float xlj[4][4];
    #pragma unroll
    for (int b = 0; b < 4; b++) {
      bool valid = (e + b) < e1;
      int j = col[valid ? e + b : e0];     // e0 always valid (self-loop)
      short4 xl4 = *(const short4*)(xlr + (size_t)j * NW + lane * 4);
      float pp = 0.f;
      #pragma unroll
      for (int k = 0; k < 4; k++) {
        xlj[b][k] = bf2f(((short*)&xl4)[k]);
        float h = xlj[b][k] + xri[k];
        float lr = h > 0.f ? h : 0.2f * h;
        pp += lr * attc[k];
      }
      p[b] = valid ? pp : -INFINITY;
    }
    #pragma unroll
    for (int off = 32; off; off >>= 1) {
      #pragma unroll
      for (int b = 0; b < 4; b++) p[b] += __shfl_xor(p[b], off);
    }
    float mn = fmaxf(m, fmaxf(fmaxf(p[0], p[1]), fmaxf(p[2], p[3])));
    float scale = __expf(m - mn);
    float w[4];
    #pragma unroll
    for (int b = 0; b < 4; b++) w[b] = __expf(p[b] - mn);
    s = s * scale + w[0] + w[1] + w[2] + w[3];
    #pragma unroll
    for (int k = 0; k < 4; k++)
      o[k] = o[k] * scale + w[0] * xlj[0][k] + w[1] * xlj[1][k]
                          + w[2] * xlj[2][k] + w[3] * xlj[3][k];
    m = mn;
  }
  float inv = 1.0f / (s + 1e-16f);
  f32x4 ov;
  #pragma unroll
  for (int k = 0; k < 4; k++) ov[k] = o[k] * inv + bias[lane * 4 + k];
  *(f32x4*)(out + (size_t)node * HID + lane * 4) = ov;
}

// ---------------------------------------------------------------- late stage
__device__ __forceinline__ float fdec(unsigned u) {
  unsigned b = (u & 0x80000000u) ? (u & 0x7FFFFFFFu) : ~u;
  return __uint_as_float(b);
}

__global__ void build_xlate(const float* __restrict__ cfg, const float* __restrict__ cmean,
                            const float* __restrict__ cstd, const float* __restrict__ psum,
                            const unsigned* __restrict__ pmax, short* __restrict__ xlateb)
{
  int i = blockIdx.x * blockDim.x + threadIdx.x;
  if (i >= N_CFG * K288) return;
  int r = i / K288, c = i % K288;
  float v;
  if (c < CFG_FEAT) v = (cfg[r * CFG_FEAT + c] - cmean[c]) / (cstd[c] + 1e-4f);
  else if (c < CFG_FEAT + HID) {
    int p = c - CFG_FEAT;
    v = psum[p] * (1.0f / N_NODES) + fdec(pmax[p]);
  } else v = 0.f;
  xlateb[i] = f2bf(v);
}

// pred with fused final norm+gelu (stats from L2 GEMM epilogue)
__global__ __launch_bounds__(64) void pred_kernel(
    const float* __restrict__ h2, const float* __restrict__ stats,
    const float* __restrict__ W, const float* __restrict__ b,
    float* __restrict__ out)
{
  int r = blockIdx.x, lane = threadIdx.x;
  const float invM = 1.0f / (float)N_CFG;
  float v = 0.f;
  #pragma unroll
  for (int t = 0; t < 2; t++) {
    int c = lane + 64 * t;
    float mean = stats[c] * invM;
    float var = stats[128 + c] * invM - mean * mean;
    float y = gelu_f((h2[(size_t)r * 128 + c] - mean) * rsqrtf(var + 1e-5f));
    v += y * W[c];
  }
  #pragma unroll
  for (int off = 32; off; off >>= 1) v += __shfl_xor(v, off);
  if (lane == 0) out[r] = v + b[0];
}

// ================================================================ launch
extern "C" void kernel_launch(void* const* d_in, const int* in_sizes, int n_in,
                              void* d_out, int out_size, void* d_ws, size_t ws_size,
                              hipStream_t stream)
{
  const float* node_feat   = (const float*)d_in[0];
  const float* config_feat = (const float*)d_in[1];
  const float* nf_mean     = (const float*)d_in[2];
  const float* nf_std      = (const float*)d_in[3];
  const float* cf_mean     = (const float*)d_in[4];
  const float* cf_std      = (const float*)d_in[5];
  const float* emb_table   = (const float*)d_in[6];
  const float* early_W1    = (const float*)d_in[7];
  const float* early_W2    = (const float*)d_in[8];
  const float* gat_Wl      = (const float*)d_in[9];
  const float* gat_bl      = (const float*)d_in[10];
  const float* gat_Wr      = (const float*)d_in[11];
  const float* gat_br      = (const float*)d_in[12];
  const float* gat_att     = (const float*)d_in[13];
  const float* gat_bias    = (const float*)d_in[14];
  const float* late_W1     = (const float*)d_in[15];
  const float* late_W2     = (const float*)d_in[16];
  const float* pred_W      = (const float*)d_in[17];
  const float* pred_b      = (const float*)d_in[18];
  const int*   node_opcode = (const int*)d_in[19];
  const int*   edge_index  = (const int*)d_in[20];
  float* out = (float*)d_out;
  (void)in_sizes; (void)n_in; (void)out_size; (void)ws_size;

  char* ws = (char*)d_ws;
  size_t off = 0;
  auto alloc = [&](size_t bytes) -> void* {
    void* p = ws + off;
    off += (bytes + 255) & ~255ull;
    return p;
  };
  short* x268b = (short*)alloc((size_t)MPAD * K288 * 2);
  float* bufB  = (float*)alloc((size_t)N_NODES * HID * 4);
  short* bufAb = (short*)alloc((size_t)MPAD * HID * 2);
  short* xlr   = (short*)alloc((size_t)N_NODES * NW * 2);
  int* indptr  = (int*)alloc((N_NODES + 1) * 4);
  int* colidx  = (int*)alloc((size_t)E_TOT * 4);
  short* xlateb = (short*)alloc((size_t)1024 * K288 * 2);
  float* h1    = (float*)alloc((size_t)N_CFG * HID * 4);
  short* h1b   = (short*)alloc((size_t)1024 * HID * 2);
  float* h2    = (float*)alloc((size_t)N_CFG * 128 * 4);
  short* W1t   = (short*)alloc((size_t)HID * K288 * 2);
  short* W2t   = (short*)alloc((size_t)HID * HID * 2);
  short* Wlrt  = (short*)alloc((size_t)4 * NW * HID * 2);
  float* blr   = (float*)alloc(4 * NW * 4);
  short* lW1t  = (short*)alloc((size_t)HID * K288 * 2);
  short* lW2t  = (short*)alloc((size_t)128 * HID * 2);

  // ---- contiguous zero region (single memset per call) ----
  float* zbase = (float*)alloc((8 * 1024 + 512 + 2 * N_NODES) * 4);
  float* stats8 = zbase;
  float* psum   = zbase + 8192;
  unsigned* pmax = (unsigned*)(zbase + 8192 + 256);
  int* counts   = (int*)(zbase + 8192 + 512);
  int* cursor   = counts + N_NODES;
  const size_t zbytes = (8 * 1024 + 512 + 2 * N_NODES) * 4;
  auto slot = [&](int s) { return stats8 + s * 1024; };
  // slots: 0=E1 1=E2 2..5=G0..G3 6=L1 7=L2

  auto run_gemm = [&](int BM, const short* A, const short* Wt, const float* bias, float* C,
                      short* Cb, float* stats, int M, int N, int Kpad) {
    if (BM == 128) {
      dim3 grid((M + 127) / 128, N / 128);
      hipLaunchKernelGGL((gemm_mfma<128, 128>), grid, dim3(256), 0, stream,
                         A, Wt, bias, C, Cb, stats, M, N, Kpad);
    } else {
      dim3 grid((M + 63) / 64, N / 64);
      hipLaunchKernelGGL((gemm_mfma<64, 64>), grid, dim3(256), 0, stream,
                         A, Wt, bias, C, Cb, stats, M, N, Kpad);
    }
  };
  auto run_norm = [&](const float* X, short* Yb, int M, int C, float* stats,
                      float* ps, unsigned* pm) {
    hipLaunchKernelGGL(norm_gelu_col, dim3((M + 31) / 32), dim3(C), 0, stream,
                       X, Yb, M, C, stats, ps, pm);
  };

  hipMemsetAsync(zbase, 0, zbytes, stream);

  // weight prep (one kernel)
  {
    int total = HID * K288 + HID * HID + HID * K288 + 128 * HID + 4 * NW * HID + 4 * NW;
    hipLaunchKernelGGL(prep_weights, dim3((total + 255) / 256), dim3(256), 0, stream,
                       early_W1, early_W2, late_W1, late_W2, gat_Wl, gat_Wr, gat_bl, gat_br,
                       W1t, W2t, lW1t, lW2t, Wlrt, blr);
  }

  // CSR build
  hipLaunchKernelGGL(edge_count, dim3((E_TOT + 255) / 256), dim3(256), 0, stream,
                     edge_index, counts);
  hipLaunchKernelGGL(scan_kernel, dim3(1), dim3(1024), 0, stream, counts, indptr);
  hipLaunchKernelGGL(edge_fill, dim3((E_TOT + 255) / 256), dim3(256), 0, stream,
                     edge_index, indptr, cursor, colidx);

  // prep + early MLP
  hipLaunchKernelGGL(prep_kernel, dim3((N_NODES + 3) / 4), dim3(256), 0, stream,
                     node_feat, nf_mean, nf_std, emb_table, node_opcode, x268b);
  run_gemm(64, x268b, W1t, nullptr, bufB, nullptr, slot(0), N_NODES, HID, K288);
  run_norm(bufB, bufAb, N_NODES, HID, slot(0), nullptr, nullptr);
  run_gemm(64, bufAb, W2t, nullptr, bufB, nullptr, slot(1), N_NODES, HID, HID);
  run_norm(bufB, bufAb, N_NODES, HID, slot(1), nullptr, nullptr);

  // 4 GAT layers
  for (int l = 0; l < 4; l++) {
    run_gemm(128, bufAb, Wlrt + (size_t)l * NW * HID, blr + l * NW, nullptr, xlr, nullptr,
             N_NODES, NW, HID);
    hipLaunchKernelGGL(gat_agg, dim3((N_NODES + 3) / 4), dim3(256), 0, stream,
                       xlr, indptr, colidx, gat_att + l * HID, gat_bias + l * HID, bufB);
    hipLaunchKernelGGL(colstats, dim3((N_NODES + 63) / 64), dim3(HID), 0, stream,
                       bufB, N_NODES, HID, slot(2 + l));
    run_norm(bufB, bufAb, N_NODES, HID, slot(2 + l),
             (l == 3) ? psum : nullptr, (l == 3) ? pmax : nullptr);
  }

  // late MLP
  hipLaunchKernelGGL(build_xlate, dim3((N_CFG * K288 + 255) / 256), dim3(256), 0, stream,
                     config_feat, cf_mean, cf_std, psum, pmax, xlateb);
  run_gemm(64, xlateb, lW1t, nullptr, h1, nullptr, slot(6), N_CFG, HID, K288);
  run_norm(h1, h1b, N_CFG, HID, slot(6), nullptr, nullptr);
  run_gemm(64, h1b, lW2t, nullptr, h2, nullptr, slot(7), N_CFG, 128, HID);
  hipLaunchKernelGGL(pred_kernel, dim3(N_CFG), dim3(64), 0, stream,
                     h2, slot(7), pred_W, pred_b, out);
}